// Round 2
// baseline (472.067 us; speedup 1.0000x reference)
//
#include <hip/hip_runtime.h>

typedef __attribute__((ext_vector_type(8))) __bf16 bf16x8;
typedef __attribute__((ext_vector_type(4))) float f32x4;

#define N_ 1024
#define C_ 64
#define BP_ 48

static __device__ __forceinline__ unsigned short f2bf(float f) {
    __bf16 b = (__bf16)f;
    return __builtin_bit_cast(unsigned short, b);
}
static __device__ __forceinline__ unsigned int pack2(float a, float b) {
    return (unsigned int)f2bf(a) | ((unsigned int)f2bf(b) << 16);
}

// ---------------------------------------------------------------------------
// K1: v1/v2 fold of W_emb, s1/s2 per node, per-wave max(s2) -> M2part, and
// bf16 transpose xT[bp][c][j].  grid (16 j-tiles, 48 bp), block 256 (4 waves).
// ---------------------------------------------------------------------------
__global__ __launch_bounds__(256) void gat_pre(
    const float* __restrict__ x, const float* __restrict__ Wemb,
    const float* __restrict__ a1, const float* __restrict__ a2,
    float* __restrict__ s1g, float* __restrict__ s2g,
    unsigned short* __restrict__ xT, float* __restrict__ M2part)
{
    __shared__ float xs[64][65];
    __shared__ float vs[2][64];
    const int t = threadIdx.x, l = t & 63, w = t >> 6;
    const int j0 = blockIdx.x * 64;
    const int bp = blockIdx.y;

    if (w == 0) {   // v1[c]=sum_h a1[h]*W_emb[h][c]  (x_emb folds away)
        float v1 = 0.f, v2 = 0.f;
        #pragma unroll 8
        for (int h = 0; h < 64; ++h) {
            float we = Wemb[h * 64 + l];
            v1 = fmaf(a1[h], we, v1);
            v2 = fmaf(a2[h], we, v2);
        }
        vs[0][l] = v1; vs[1][l] = v2;
    }
    const float* xb = x + ((size_t)bp * N_ + j0) * C_;
    #pragma unroll
    for (int it = 0; it < 16; ++it)
        xs[it * 4 + w][l] = xb[(it * 4 + w) * C_ + l];
    __syncthreads();

    const int jr = t >> 2, c0 = (t & 3) * 16;
    float p1 = 0.f, p2 = 0.f;
    #pragma unroll
    for (int k = 0; k < 16; ++k) {
        float xv = xs[jr][c0 + k];
        p1 = fmaf(xv, vs[0][c0 + k], p1);
        p2 = fmaf(xv, vs[1][c0 + k], p2);
    }
    p1 += __shfl_xor(p1, 1); p1 += __shfl_xor(p1, 2);
    p2 += __shfl_xor(p2, 1); p2 += __shfl_xor(p2, 2);
    if ((l & 3) == 0) {
        s1g[bp * N_ + j0 + jr] = p1;
        s2g[bp * N_ + j0 + jr] = p2;
    }
    float m = p2;
    m = fmaxf(m, __shfl_xor(m, 4));
    m = fmaxf(m, __shfl_xor(m, 8));
    m = fmaxf(m, __shfl_xor(m, 16));
    m = fmaxf(m, __shfl_xor(m, 32));
    if (l == 0) M2part[bp * 64 + blockIdx.x * 4 + w] = m;

    const int c = t >> 2, part = t & 3;
    unsigned int ow[8];
    #pragma unroll
    for (int k = 0; k < 16; k += 2) {
        unsigned int lo = f2bf(xs[part * 16 + k][c]);
        unsigned int hi = f2bf(xs[part * 16 + k + 1][c]);
        ow[k >> 1] = lo | (hi << 16);
    }
    uint4* dst = (uint4*)(xT + (size_t)bp * C_ * N_ + (size_t)c * N_ + j0 + part * 16);
    dst[0] = make_uint4(ow[0], ow[1], ow[2], ow[3]);
    dst[1] = make_uint4(ow[4], ow[5], ow[6], ow[7]);
}

// ---------------------------------------------------------------------------
// K2 v3: split-j flash.  Round-1 counters: everything idle (Mfma 1.9%,
// VALU 13%, HBM 31%, Occ 32%) -> latency-bound, and occupancy is GRID-
// limited (768 blocks = 3 blocks/CU).  Fix: each block = 2 row-groups x
// 2 j-halves (32 rows, 4 waves); grid (32,48) = 1536 blocks = 6 blocks/CU
// = 24 waves/CU, each wave only 8 chunks.  The softmax shift uses the
// GLOBAL row max M2, so the two j-half partials combine by plain addition
// (acc+=, ls+=) through a padded LDS buffer - no rescale needed.
// ---------------------------------------------------------------------------
__global__ __launch_bounds__(256, 6) void gat_fused(
    const float* __restrict__ Ag, float* __restrict__ outA,
    const unsigned short* __restrict__ xT,
    const float* __restrict__ s1g, const float* __restrict__ s2g,
    const float* __restrict__ M2part,
    const float* __restrict__ Wlin, float* __restrict__ out)
{
    __shared__ unsigned short Plds[4][16][72];  // 9 KB   per-wave P tile (pad 8)
    __shared__ float s2lds[1024];               // 4 KB   s2 row, block-shared
    __shared__ float lsLDS[4][16];              // 256 B  per-wave row sums
    __shared__ float comb[2][16][68];           // 8.5 KB pair-combine (pad 4)

    const int t = threadIdx.x, l = t & 63, w = t >> 6;
    const int i15 = l & 15, q = l >> 4;
    const int lm = l & 15, g16 = l >> 4;
    const int bp = blockIdx.y;
    const int rg = w >> 1, jh = w & 1;          // row-group, j-half
    const int ibase = blockIdx.x * 32 + rg * 16;
    const int jbase = jh * 512;

    // stage s2 (1024 f32) to LDS, block-wide
    *(f32x4*)&s2lds[4 * t] = *(const f32x4*)&s2g[bp * N_ + 4 * t];

    float m2v = M2part[bp * 64 + l];
    #pragma unroll
    for (int off = 32; off >= 1; off >>= 1)
        m2v = fmaxf(m2v, __shfl_xor(m2v, off));
    const float M2 = m2v;
    const float s1_l = s1g[bp * N_ + ibase + i15];   // lane rr holds s1 of row rr

    // k-invariant per-row constants: s1 of rows 4*sr+g16 and softmax shift
    float s1r[4], mvr[4];
    #pragma unroll
    for (int sr = 0; sr < 4; ++sr) {
        s1r[sr] = __shfl(s1_l, 4 * sr + g16);
        float zr = s1r[sr] + M2;
        mvr[sr] = fmaxf(zr, 0.01f * zr);   // = max_j leaky(s1+s2j) upper bound
    }

    __syncthreads();   // s2lds ready

    // lane-resolved base pointers: row (ibase+g16), col jbase + 4*lm
    const float* Arow = Ag + ((size_t)bp * N_ + ibase + g16) * N_ + jbase + 4 * lm;
    float* oArow = outA + ((size_t)bp * N_ + ibase + g16) * N_ + jbase + 4 * lm;
    const unsigned short* xTb = xT + (size_t)bp * C_ * N_;

    f32x4 acc[4] = {};                  // rows q*4+r, c = nt*16+i15
    float ls4[4] = {0.f, 0.f, 0.f, 0.f};

    f32x4 Aa0, Aa1, Aa2, Aa3, Ab0, Ab1, Ab2, Ab3;

#define LOADA(d0, d1, d2, d3, kk) do {                                        \
    const float* _p = Arow + (kk) * 64;                                       \
    d0 = *(const f32x4*)(_p);                                                 \
    d1 = *(const f32x4*)(_p + 4 * N_);                                        \
    d2 = *(const f32x4*)(_p + 8 * N_);                                        \
    d3 = *(const f32x4*)(_p + 12 * N_); } while (0)

#define DOSR(Av, sr, jrel) do {                                               \
    *(f32x4*)(oArow + (sr) * 4 * N_ + (jrel)) = Av;                           \
    float e0, e1, e2, e3;                                                     \
    { float zz = s1r[sr] + s2v[0]; zz = fmaxf(zz, 0.01f * zz);                \
      e0 = (Av[0] != 0.f) ? __expf(zz - mvr[sr]) : 0.f; }                     \
    { float zz = s1r[sr] + s2v[1]; zz = fmaxf(zz, 0.01f * zz);                \
      e1 = (Av[1] != 0.f) ? __expf(zz - mvr[sr]) : 0.f; }                     \
    { float zz = s1r[sr] + s2v[2]; zz = fmaxf(zz, 0.01f * zz);                \
      e2 = (Av[2] != 0.f) ? __expf(zz - mvr[sr]) : 0.f; }                     \
    { float zz = s1r[sr] + s2v[3]; zz = fmaxf(zz, 0.01f * zz);                \
      e3 = (Av[3] != 0.f) ? __expf(zz - mvr[sr]) : 0.f; }                     \
    ls4[sr] += (e0 + e1) + (e2 + e3);                                         \
    *(uint2*)&Plds[w][4 * (sr) + g16][4 * lm] =                               \
        make_uint2(pack2(e0, e1), pack2(e2, e3)); } while (0)

#define CONSUME(a0, a1, a2, a3, kk) do {                                      \
    const int jrel = (kk) * 64;                                               \
    const int j0c = jbase + jrel;                                             \
    const f32x4 s2v = *(const f32x4*)&s2lds[j0c + 4 * lm];                    \
    DOSR(a0, 0, jrel); DOSR(a1, 1, jrel); DOSR(a2, 2, jrel); DOSR(a3, 3, jrel); \
    _Pragma("unroll")                                                         \
    for (int s = 0; s < 2; ++s) {                                             \
        bf16x8 af = *(const bf16x8*)&Plds[w][i15][s * 32 + q * 8];            \
        _Pragma("unroll")                                                     \
        for (int nt = 0; nt < 4; ++nt) {                                      \
            bf16x8 bfr = *(const bf16x8*)&xTb[(size_t)(nt * 16 + i15) * N_ +  \
                                              j0c + s * 32 + q * 8];          \
            acc[nt] = __builtin_amdgcn_mfma_f32_16x16x32_bf16(af, bfr,        \
                                                              acc[nt], 0, 0, 0); \
        }                                                                     \
    } } while (0)

    LOADA(Aa0, Aa1, Aa2, Aa3, 0);
    #pragma unroll 1
    for (int k = 0; k < 8; k += 2) {
        LOADA(Ab0, Ab1, Ab2, Ab3, k + 1);      // prefetch odd chunk
        CONSUME(Aa0, Aa1, Aa2, Aa3, k);        // counted wait on Aa only
        if (k + 2 < 8)
            LOADA(Aa0, Aa1, Aa2, Aa3, k + 2);  // prefetch next even chunk
        CONSUME(Ab0, Ab1, Ab2, Ab3, k + 1);    // counted wait on Ab only
    }
#undef LOADA
#undef DOSR
#undef CONSUME

    // lsum: reduce within 16-lane group (4 shuffles/row-set)
    #pragma unroll
    for (int sr = 0; sr < 4; ++sr) {
        ls4[sr] += __shfl_xor(ls4[sr], 1);
        ls4[sr] += __shfl_xor(ls4[sr], 2);
        ls4[sr] += __shfl_xor(ls4[sr], 4);
        ls4[sr] += __shfl_xor(ls4[sr], 8);
    }
    if (lm == 0) {
        #pragma unroll
        for (int sr = 0; sr < 4; ++sr)
            lsLDS[w][4 * sr + g16] = ls4[sr];
    }
    // j-half 1 waves publish their acc partial (padded stride 68 -> 2-way max)
    if (jh == 1) {
        #pragma unroll
        for (int nt = 0; nt < 4; ++nt)
            #pragma unroll
            for (int r = 0; r < 4; ++r)
                comb[rg][q * 4 + r][nt * 16 + i15] = acc[nt][r];
    }
    __syncthreads();   // partials visible
    if (jh == 1) return;

    // j-half 0 waves: merge partner partials
    #pragma unroll
    for (int nt = 0; nt < 4; ++nt)
        #pragma unroll
        for (int r = 0; r < 4; ++r)
            acc[nt][r] += comb[rg][q * 4 + r][nt * 16 + i15];
    const f32x4 ls_a = *(const f32x4*)&lsLDS[w][4 * q];
    const f32x4 ls_b = *(const f32x4*)&lsLDS[w + 1][4 * q];
    f32x4 lsq;
    #pragma unroll
    for (int r = 0; r < 4; ++r) lsq[r] = ls_a[r] + ls_b[r];

    // ---- epilogue: agg = acc/l, LDS round-trip to A-layout, @W_lin^T, sigmoid
    unsigned short* aggl = &Plds[w][0][0];   // reuse own P slice, stride 72
    #pragma unroll
    for (int nt = 0; nt < 4; ++nt)
        #pragma unroll
        for (int r = 0; r < 4; ++r)
            aggl[(q * 4 + r) * 72 + nt * 16 + i15] = f2bf(acc[nt][r] / lsq[r]);

    f32x4 d2[4] = {};
    #pragma unroll
    for (int s = 0; s < 2; ++s) {
        bf16x8 af = *(const bf16x8*)&aggl[i15 * 72 + s * 32 + q * 8];
        #pragma unroll
        for (int nt = 0; nt < 4; ++nt) {
            const float* wp = Wlin + (size_t)(nt * 16 + i15) * C_ + s * 32 + q * 8;
            f32x4 w0 = *(const f32x4*)wp;
            f32x4 w1 = *(const f32x4*)(wp + 4);
            bf16x8 bfr;
            #pragma unroll
            for (int jj = 0; jj < 4; ++jj) { bfr[jj] = (__bf16)w0[jj]; bfr[4 + jj] = (__bf16)w1[jj]; }
            d2[nt] = __builtin_amdgcn_mfma_f32_16x16x32_bf16(af, bfr, d2[nt], 0, 0, 0);
        }
    }
    float* orow = out + ((size_t)bp * N_ + ibase) * C_;
    #pragma unroll
    for (int nt = 0; nt < 4; ++nt)
        #pragma unroll
        for (int r = 0; r < 4; ++r)
            orow[(size_t)(q * 4 + r) * C_ + nt * 16 + i15] =
                1.f / (1.f + __expf(-d2[nt][r]));
}

extern "C" void kernel_launch(void* const* d_in, const int* in_sizes, int n_in,
                              void* d_out, int out_size, void* d_ws, size_t ws_size,
                              hipStream_t stream) {
    const float* x    = (const float*)d_in[0];
    const float* Ag   = (const float*)d_in[1];
    const float* Wemb = (const float*)d_in[2];
    const float* a1   = (const float*)d_in[3];
    const float* a2   = (const float*)d_in[4];
    const float* Wlin = (const float*)d_in[5];
    float* out  = (float*)d_out;
    float* outA = out + (size_t)BP_ * N_ * C_;   // tuple output #2: A passthrough

    // ws layout (~6.7 MB total)
    float* s1g = (float*)d_ws;                               // 48K f32
    float* s2g = s1g + BP_ * N_;                             // 48K f32
    float* M2part = s2g + BP_ * N_;                          // 48*64 f32
    unsigned short* xT = (unsigned short*)(M2part + BP_ * 64);   // 6.3MB bf16

    gat_pre<<<dim3(16, BP_), dim3(256), 0, stream>>>(x, Wemb, a1, a2,
                                                     s1g, s2g, xT, M2part);
    gat_fused<<<dim3(32, BP_), dim3(256), 0, stream>>>(Ag, outA, xT, s1g, s2g,
                                                       M2part, Wlin, out);
}

// Round 3
// 387.920 us; speedup vs baseline: 1.2169x; 1.2169x over previous
//
#include <hip/hip_runtime.h>

typedef __attribute__((ext_vector_type(8))) __bf16 bf16x8;
typedef __attribute__((ext_vector_type(4))) float f32x4;

#define N_ 1024
#define C_ 64
#define BP_ 48

static __device__ __forceinline__ unsigned short f2bf(float f) {
    __bf16 b = (__bf16)f;
    return __builtin_bit_cast(unsigned short, b);
}
static __device__ __forceinline__ unsigned int pack2(float a, float b) {
    return (unsigned int)f2bf(a) | ((unsigned int)f2bf(b) << 16);
}

// ---------------------------------------------------------------------------
// K1: v1/v2 fold of W_emb, s1/s2 per node, per-wave max(s2) -> M2part, and
// bf16 transpose xT[bp][c][j].  grid (16 j-tiles, 48 bp), block 256 (4 waves).
// ---------------------------------------------------------------------------
__global__ __launch_bounds__(256) void gat_pre(
    const float* __restrict__ x, const float* __restrict__ Wemb,
    const float* __restrict__ a1, const float* __restrict__ a2,
    float* __restrict__ s1g, float* __restrict__ s2g,
    unsigned short* __restrict__ xT, float* __restrict__ M2part)
{
    __shared__ float xs[64][65];
    __shared__ float vs[2][64];
    const int t = threadIdx.x, l = t & 63, w = t >> 6;
    const int j0 = blockIdx.x * 64;
    const int bp = blockIdx.y;

    if (w == 0) {   // v1[c]=sum_h a1[h]*W_emb[h][c]  (x_emb folds away)
        float v1 = 0.f, v2 = 0.f;
        #pragma unroll 8
        for (int h = 0; h < 64; ++h) {
            float we = Wemb[h * 64 + l];
            v1 = fmaf(a1[h], we, v1);
            v2 = fmaf(a2[h], we, v2);
        }
        vs[0][l] = v1; vs[1][l] = v2;
    }
    const float* xb = x + ((size_t)bp * N_ + j0) * C_;
    #pragma unroll
    for (int it = 0; it < 16; ++it)
        xs[it * 4 + w][l] = xb[(it * 4 + w) * C_ + l];
    __syncthreads();

    const int jr = t >> 2, c0 = (t & 3) * 16;
    float p1 = 0.f, p2 = 0.f;
    #pragma unroll
    for (int k = 0; k < 16; ++k) {
        float xv = xs[jr][c0 + k];
        p1 = fmaf(xv, vs[0][c0 + k], p1);
        p2 = fmaf(xv, vs[1][c0 + k], p2);
    }
    p1 += __shfl_xor(p1, 1); p1 += __shfl_xor(p1, 2);
    p2 += __shfl_xor(p2, 1); p2 += __shfl_xor(p2, 2);
    if ((l & 3) == 0) {
        s1g[bp * N_ + j0 + jr] = p1;
        s2g[bp * N_ + j0 + jr] = p2;
    }
    float m = p2;
    m = fmaxf(m, __shfl_xor(m, 4));
    m = fmaxf(m, __shfl_xor(m, 8));
    m = fmaxf(m, __shfl_xor(m, 16));
    m = fmaxf(m, __shfl_xor(m, 32));
    if (l == 0) M2part[bp * 64 + blockIdx.x * 4 + w] = m;

    const int c = t >> 2, part = t & 3;
    unsigned int ow[8];
    #pragma unroll
    for (int k = 0; k < 16; k += 2) {
        unsigned int lo = f2bf(xs[part * 16 + k][c]);
        unsigned int hi = f2bf(xs[part * 16 + k + 1][c]);
        ow[k >> 1] = lo | (hi << 16);
    }
    uint4* dst = (uint4*)(xT + (size_t)bp * C_ * N_ + (size_t)c * N_ + j0 + part * 16);
    dst[0] = make_uint4(ow[0], ow[1], ow[2], ow[3]);
    dst[1] = make_uint4(ow[4], ow[5], ow[6], ow[7]);
}

// ---------------------------------------------------------------------------
// K2 v4: store-decoupled, full register prefetch.
// R2 post-mortem: launch_bounds(256,6) capped VGPR at 85 -> scratch spills
// (VGPR=40, FETCH/WRITE both +~190MB) -> regression.  Occupancy thesis was
// confirmed (62% occ -> 3.07 TB/s) but spill bytes ate the win.
// R0/R1 stall theory: stores and loads share in-order vmcnt.  Old CONSUME
// issued 4 outA stores BEFORE the 8 xT loads, so every xT-load wait also
// drained the stores -> ~6.8k cy/chunk serialization (VALU 13%, Mfma 2%).
// Fix: prefetch A AND xT for chunk k+1 into regs FIRST, then stores+exp,
// then MFMA on the PREVIOUS chunk's xT regs.  Loads are always older than
// the stores that follow them; waits for loads never drain stores, and
// every load has a full chunk (~1000cy) of issue-to-use distance.
// NT hints on streaming A/outA keep xT resident in L2.
// grid (16,48), block 256 (4 indep waves), launch_bounds(256,3): cap 170
// VGPR, ~155 used, 12 waves/CU, NO spill.
// ---------------------------------------------------------------------------
__global__ __launch_bounds__(256, 3) void gat_fused(
    const float* __restrict__ Ag, float* __restrict__ outA,
    const unsigned short* __restrict__ xT,
    const float* __restrict__ s1g, const float* __restrict__ s2g,
    const float* __restrict__ M2part,
    const float* __restrict__ Wlin, float* __restrict__ out)
{
    __shared__ unsigned short Plds[4][16][72];  // 9 KB   per-wave P tile (pad 8)
    __shared__ float s2lds[1024];               // 4 KB   s2 row, block-shared
    __shared__ float lsLDS[4][16];              // 256 B  per-wave row sums

    const int t = threadIdx.x, l = t & 63, w = t >> 6;
    const int i15 = l & 15, q = l >> 4;
    const int lm = l & 15, g16 = l >> 4;
    const int bp = blockIdx.y;
    const int ibase = blockIdx.x * 64 + w * 16;

    // stage s2 (1024 f32) to LDS, block-wide
    *(f32x4*)&s2lds[4 * t] = *(const f32x4*)&s2g[bp * N_ + 4 * t];

    float m2v = M2part[bp * 64 + l];
    #pragma unroll
    for (int off = 32; off >= 1; off >>= 1)
        m2v = fmaxf(m2v, __shfl_xor(m2v, off));
    const float M2 = m2v;
    const float s1_l = s1g[bp * N_ + ibase + i15];   // lane rr holds s1 of row rr

    // k-invariant per-row constants: s1 of rows 4*sr+g16 and softmax shift
    float s1r[4], mvr[4];
    #pragma unroll
    for (int sr = 0; sr < 4; ++sr) {
        s1r[sr] = __shfl(s1_l, 4 * sr + g16);
        float zr = s1r[sr] + M2;
        mvr[sr] = fmaxf(zr, 0.01f * zr);   // = max_j leaky(s1+s2j) upper bound
    }

    __syncthreads();   // s2lds ready (only barrier in the kernel)

    // lane-resolved base pointers: row (ibase+g16), col 4*lm
    const float* Arow = Ag + ((size_t)bp * N_ + ibase + g16) * N_ + 4 * lm;
    float* oArow = outA + ((size_t)bp * N_ + ibase + g16) * N_ + 4 * lm;
    // xT fragment base for this lane: row i15 (+nt*16), byte col q*8 (+k*64+s*32)
    const unsigned short* xTrow = xT + (size_t)bp * C_ * N_ + (size_t)i15 * N_ + q * 8;

    f32x4 acc[4] = {};                  // rows q*4+r, c = nt*16+i15
    float ls4[4] = {0.f, 0.f, 0.f, 0.f};

    f32x4 Aa[4], Ab[4];                 // A chunk double-buffer (32 VGPR)
    bf16x8 Xa[8], Xb[8];                // xT chunk double-buffer (64 VGPR)
    // (all indices below are compile-time after unroll -> stays in registers)

#define LOADX(X, kk) do {                                                     \
    _Pragma("unroll")                                                         \
    for (int nt = 0; nt < 4; ++nt)                                            \
        _Pragma("unroll")                                                     \
        for (int s = 0; s < 2; ++s)                                           \
            X[s * 4 + nt] = *(const bf16x8*)&xTrow[(size_t)nt * 16 * N_ +     \
                                                   (kk) * 64 + s * 32];       \
    } while (0)

#define LOADA(Ax, kk) do {                                                    \
    const float* _p = Arow + (kk) * 64;                                       \
    _Pragma("unroll")                                                         \
    for (int r = 0; r < 4; ++r)                                               \
        Ax[r] = __builtin_nontemporal_load((const f32x4*)(_p + r * 4 * N_));  \
    } while (0)

#define DOSR(Av, sr, jrel) do {                                               \
    __builtin_nontemporal_store(Av, (f32x4*)(oArow + (sr) * 4 * N_ + (jrel)));\
    float e0, e1, e2, e3;                                                     \
    { float zz = s1r[sr] + s2v[0]; zz = fmaxf(zz, 0.01f * zz);                \
      e0 = (Av[0] != 0.f) ? __expf(zz - mvr[sr]) : 0.f; }                     \
    { float zz = s1r[sr] + s2v[1]; zz = fmaxf(zz, 0.01f * zz);                \
      e1 = (Av[1] != 0.f) ? __expf(zz - mvr[sr]) : 0.f; }                     \
    { float zz = s1r[sr] + s2v[2]; zz = fmaxf(zz, 0.01f * zz);                \
      e2 = (Av[2] != 0.f) ? __expf(zz - mvr[sr]) : 0.f; }                     \
    { float zz = s1r[sr] + s2v[3]; zz = fmaxf(zz, 0.01f * zz);                \
      e3 = (Av[3] != 0.f) ? __expf(zz - mvr[sr]) : 0.f; }                     \
    ls4[sr] += (e0 + e1) + (e2 + e3);                                         \
    *(uint2*)&Plds[w][4 * (sr) + g16][4 * lm] =                               \
        make_uint2(pack2(e0, e1), pack2(e2, e3)); } while (0)

// consume chunk kk from register buffers X (xT) and Ac (A)
#define CONSUME(X, Ac, kk) do {                                               \
    const int jrel = (kk) * 64;                                               \
    const f32x4 s2v = *(const f32x4*)&s2lds[jrel + 4 * lm];                   \
    DOSR(Ac[0], 0, jrel); DOSR(Ac[1], 1, jrel);                               \
    DOSR(Ac[2], 2, jrel); DOSR(Ac[3], 3, jrel);                               \
    _Pragma("unroll")                                                         \
    for (int s = 0; s < 2; ++s) {                                             \
        bf16x8 af = *(const bf16x8*)&Plds[w][i15][s * 32 + q * 8];            \
        _Pragma("unroll")                                                     \
        for (int nt = 0; nt < 4; ++nt)                                        \
            acc[nt] = __builtin_amdgcn_mfma_f32_16x16x32_bf16(af, X[s * 4 + nt], \
                                                              acc[nt], 0, 0, 0); \
    } } while (0)

    // prime chunk 0
    LOADX(Xa, 0); LOADA(Aa, 0);
    #pragma unroll 1
    for (int k = 0; k < 16; k += 2) {
        LOADX(Xb, k + 1); LOADA(Ab, k + 1);   // prefetch BEFORE any store
        CONSUME(Xa, Aa, k);
        if (k + 2 < 16) { LOADX(Xa, k + 2); LOADA(Aa, k + 2); }
        CONSUME(Xb, Ab, k + 1);
    }
#undef LOADX
#undef LOADA
#undef DOSR
#undef CONSUME

    // lsum: reduce within 16-lane group (4 shuffles/row-set), exchange via LDS
    #pragma unroll
    for (int sr = 0; sr < 4; ++sr) {
        ls4[sr] += __shfl_xor(ls4[sr], 1);
        ls4[sr] += __shfl_xor(ls4[sr], 2);
        ls4[sr] += __shfl_xor(ls4[sr], 4);
        ls4[sr] += __shfl_xor(ls4[sr], 8);
    }
    if (lm == 0) {
        #pragma unroll
        for (int sr = 0; sr < 4; ++sr)
            lsLDS[w][4 * sr + g16] = ls4[sr];
    }
    const f32x4 lsq = *(const f32x4*)&lsLDS[w][4 * q];   // rows 4q..4q+3

    // ---- epilogue: agg = acc/l, LDS round-trip to A-layout, @W_lin^T, sigmoid
    unsigned short* aggl = &Plds[w][0][0];   // reuse P slice, stride 72
    #pragma unroll
    for (int nt = 0; nt < 4; ++nt)
        #pragma unroll
        for (int r = 0; r < 4; ++r)
            aggl[(q * 4 + r) * 72 + nt * 16 + i15] = f2bf(acc[nt][r] / lsq[r]);

    f32x4 d2[4] = {};
    #pragma unroll
    for (int s = 0; s < 2; ++s) {
        bf16x8 af = *(const bf16x8*)&aggl[i15 * 72 + s * 32 + q * 8];
        #pragma unroll
        for (int nt = 0; nt < 4; ++nt) {
            const float* wp = Wlin + (size_t)(nt * 16 + i15) * C_ + s * 32 + q * 8;
            f32x4 w0 = *(const f32x4*)wp;
            f32x4 w1 = *(const f32x4*)(wp + 4);
            bf16x8 bfr;
            #pragma unroll
            for (int jj = 0; jj < 4; ++jj) { bfr[jj] = (__bf16)w0[jj]; bfr[4 + jj] = (__bf16)w1[jj]; }
            d2[nt] = __builtin_amdgcn_mfma_f32_16x16x32_bf16(af, bfr, d2[nt], 0, 0, 0);
        }
    }
    float* orow = out + ((size_t)bp * N_ + ibase) * C_;
    #pragma unroll
    for (int nt = 0; nt < 4; ++nt)
        #pragma unroll
        for (int r = 0; r < 4; ++r)
            orow[(size_t)(q * 4 + r) * C_ + nt * 16 + i15] =
                1.f / (1.f + __expf(-d2[nt][r]));
}

extern "C" void kernel_launch(void* const* d_in, const int* in_sizes, int n_in,
                              void* d_out, int out_size, void* d_ws, size_t ws_size,
                              hipStream_t stream) {
    const float* x    = (const float*)d_in[0];
    const float* Ag   = (const float*)d_in[1];
    const float* Wemb = (const float*)d_in[2];
    const float* a1   = (const float*)d_in[3];
    const float* a2   = (const float*)d_in[4];
    const float* Wlin = (const float*)d_in[5];
    float* out  = (float*)d_out;
    float* outA = out + (size_t)BP_ * N_ * C_;   // tuple output #2: A passthrough

    // ws layout (~6.7 MB total)
    float* s1g = (float*)d_ws;                               // 48K f32
    float* s2g = s1g + BP_ * N_;                             // 48K f32
    float* M2part = s2g + BP_ * N_;                          // 48*64 f32
    unsigned short* xT = (unsigned short*)(M2part + BP_ * 64);   // 6.3MB bf16

    gat_pre<<<dim3(16, BP_), dim3(256), 0, stream>>>(x, Wemb, a1, a2,
                                                     s1g, s2g, xT, M2part);
    gat_fused<<<dim3(16, BP_), dim3(256), 0, stream>>>(Ag, outA, xT, s1g, s2g,
                                                       M2part, Wlin, out);
}